// Round 1
// baseline (283.319 us; speedup 1.0000x reference)
//
#include <hip/hip_runtime.h>

// ROI align (14x14 bilinear grid per proposal/channel) + 2x2 maxpool -> 7x7.
// B=4, N=512, C=256, feature plane 50x50 f32, out (4,512,256,7,7) f32.
//
// One block per (b,n). Row/col interp indices+fracs are uniform per block.
// Physical rows x..x+w (<=23) streamed via 2-slot LDS ring buffer:
//   stage: coalesced global->LDS copy of row segment [y, y+h] for all 256 ch
//   compute: thread c col-lerps its channel's row into regs (M0/M1 cache),
//            then row-lerp + pairwise max -> pooled output.
// Clamp (high = min(low+1, len-1)) folded into frac (=0 at boundary); the +1
// neighbor read is always staged/valid since we stage w+1 rows, h+1 cols
// (x+w <= 44 < 50, y+h <= 44 < 50 given proposals < 360 * 0.0625 = 22.5).

#define HPAD 25              // per-channel LDS row stride (odd -> bank-safe)
#define SLOT (256 * HPAD)    // one row-slot: 256 channels

__global__ __launch_bounds__(256) void roi_kernel(
    const float* __restrict__ proposals,   // (4,512,4)  [x,y,w,h]
    const float* __restrict__ features,    // (4,256,50,50)
    float* __restrict__ out)               // (4,512,256,7,7)
{
    const int bid = blockIdx.x;            // 0..2047 = b*512+n
    const int b   = bid >> 9;
    const int tid = threadIdx.x;

    __shared__ float s_cf[16];
    __shared__ int   s_cl[16];
    __shared__ float s_rf[16];
    __shared__ int   s_rl[16];
    __shared__ float slots[2 * SLOT];      // 51200 B

    // ---- proposal -> integer box (must match numpy f32 semantics) ----
    const float4 prop = *(const float4*)(proposals + (size_t)bid * 4);
    const int x = (int)(prop.x * 0.0625f);   // row start   (Hf/IMG = 50/800)
    const int y = (int)(prop.y * 0.0625f);   // col start
    const int w = (int)(prop.z * 0.0625f);   // row extent  (>=5, <=22)
    const int h = (int)(prop.w * 0.0625f);   // col extent  (>=5, <=22)

    if (tid < 14) {
        const float sc = (float)(w - 1) / 13.0f;
        const float c  = (float)tid * sc;
        const int lo   = (int)c;
        s_rl[tid] = lo;                                  // local row (0-based)
        s_rf[tid] = (lo + 1 > w - 1) ? 0.0f : (c - (float)lo);
    } else if (tid >= 64 && tid < 78) {
        const int j    = tid - 64;
        const float sc = (float)(h - 1) / 13.0f;
        const float c  = (float)j * sc;
        const int lo   = (int)c;
        s_cl[j] = lo;                                    // local col (0-based)
        s_cf[j] = (lo + 1 > h - 1) ? 0.0f : (c - (float)lo);
    }
    __syncthreads();

    // per-thread copies: col fracs + LDS offsets for this thread's channel
    float cf[14]; int cof[14];
    #pragma unroll
    for (int j = 0; j < 14; ++j) {
        cf[j]  = s_cf[j];
        cof[j] = tid * HPAD + s_cl[j];
    }

    // ---- staging setup: lanes = (channel-group 0..7) x (col 0..31) ----
    const int span = h + 1;                // cols staged per row: y .. y+h
    const int col  = tid & 31;
    const int cg   = tid >> 5;             // channel = cg + 8*k, k=0..31
    const float* fb = features + ((size_t)b * 256 + cg) * 2500
                               + (size_t)x * 50 + y + col;

    auto stage = [&](int p, int s) {
        if (col < span) {
            const float* g = fb + p * 50;
            float* d = slots + s * SLOT + cg * HPAD + col;
            #pragma unroll
            for (int k = 0; k < 32; ++k) {
                d[k * 8 * HPAD] = g[k * 8 * 2500];
            }
        }
    };

    // col-lerp one staged physical row into M[14] for this thread's channel
    auto collerp = [&](int s, float* M) {
        const float* sb = slots + s * SLOT;
        #pragma unroll
        for (int j = 0; j < 14; ++j) {
            const float lo = sb[cof[j]];
            const float hi = sb[cof[j] + 1];   // cl+1 <= h: always staged
            M[j] = lo + cf[j] * (hi - lo);     // frac==0 when clamped
        }
    };

    // ---- main: stream physical rows 0..w, emit interp rows on the fly ----
    float M0[14], M1[14], pool7[7];
    stage(0, 0);
    __syncthreads();
    collerp(0, M1);                         // M1 = physical row 0

    float* outp = out + ((size_t)bid * 256 + tid) * 49;
    int i = 0;                              // interp-row pointer (uniform)
    for (int p = 1; p <= w; ++p) {
        #pragma unroll
        for (int j = 0; j < 14; ++j) M0[j] = M1[j];
        __syncthreads();                    // everyone done reading slot p&1
        stage(p, p & 1);
        __syncthreads();
        collerp(p & 1, M1);                 // M1 = physical row p
        // emit all interp rows whose low row == p-1 (rl non-decreasing)
        while (i < 14 && s_rl[i] == p - 1) {
            const float rf = s_rf[i];
            float v[14];
            #pragma unroll
            for (int j = 0; j < 14; ++j) v[j] = M0[j] + rf * (M1[j] - M0[j]);
            #pragma unroll
            for (int q = 0; q < 7; ++q) {
                const float m = fmaxf(v[2 * q], v[2 * q + 1]);
                if (i & 1) outp[(i >> 1) * 7 + q] = fmaxf(pool7[q], m);
                else       pool7[q] = m;
            }
            ++i;
        }
    }
}

extern "C" void kernel_launch(void* const* d_in, const int* in_sizes, int n_in,
                              void* d_out, int out_size, void* d_ws, size_t ws_size,
                              hipStream_t stream) {
    const float* proposals = (const float*)d_in[0];   // (4,512,4)
    const float* features  = (const float*)d_in[1];   // (4,256,50,50)
    float* outp = (float*)d_out;                      // 25,690,112 floats
    roi_kernel<<<dim3(2048), dim3(256), 0, stream>>>(proposals, features, outp);
}

// Round 2
// 259.109 us; speedup vs baseline: 1.0934x; 1.0934x over previous
//
#include <hip/hip_runtime.h>

// ROI align (14x14 bilinear grid per proposal/channel) + 2x2 maxpool -> 7x7.
// B=4, N=512, C=256, feature plane 50x50 f32, out (4,512,256,7,7) f32.
//
// One block per (b,n). Row/col interp indices+fracs are uniform per block.
// Physical rows x..x+w (<=23) streamed via 2-slot LDS ring buffer:
//   stage: coalesced global->LDS copy of row segment [y, y+h] for all 256 ch
//   compute: thread c col-lerps its channel's row into regs (M0/M1 cache),
//            then row-lerp + pairwise max -> res[49] in registers.
// R1 lesson: streaming 7-float dribbles straight to global caused 2.6x write
// amplification + 100 MB of write-allocate RMW fetch (263 MB WRITE / 160 MB
// FETCH for a 103 MB output). Now: buffer 49 outputs in regs, then stage the
// block's contiguous 50 KB output region through LDS and store with
// lane-consecutive float4 -> full-line writes only.

#define HPAD 25              // per-channel LDS row stride (odd -> bank-safe)
#define SLOT (256 * HPAD)    // one row-slot: 256 channels

__global__ __launch_bounds__(256) void roi_kernel(
    const float* __restrict__ proposals,   // (4,512,4)  [x,y,w,h]
    const float* __restrict__ features,    // (4,256,50,50)
    float* __restrict__ out)               // (4,512,256,7,7)
{
    const int bid = blockIdx.x;            // 0..2047 = b*512+n
    const int b   = bid >> 9;
    const int tid = threadIdx.x;

    __shared__ float s_cf[16];
    __shared__ int   s_cl[16];
    __shared__ float s_rf[16];
    __shared__ int   s_rl[16];
    __shared__ float slots[2 * SLOT];      // 51200 B; reused for store staging

    // ---- proposal -> integer box (must match numpy f32 semantics) ----
    const float4 prop = *(const float4*)(proposals + (size_t)bid * 4);
    const int x = (int)(prop.x * 0.0625f);   // row start   (Hf/IMG = 50/800)
    const int y = (int)(prop.y * 0.0625f);   // col start
    const int w = (int)(prop.z * 0.0625f);   // row extent  (>=5, <=22)
    const int h = (int)(prop.w * 0.0625f);   // col extent  (>=5, <=22)

    if (tid < 14) {
        const float sc = (float)(w - 1) / 13.0f;
        const float c  = (float)tid * sc;
        const int lo   = (int)c;
        s_rl[tid] = lo;                                  // local row (0-based)
        s_rf[tid] = (lo + 1 > w - 1) ? 0.0f : (c - (float)lo);
    } else if (tid >= 64 && tid < 78) {
        const int j    = tid - 64;
        const float sc = (float)(h - 1) / 13.0f;
        const float c  = (float)j * sc;
        const int lo   = (int)c;
        s_cl[j] = lo;                                    // local col (0-based)
        s_cf[j] = (lo + 1 > h - 1) ? 0.0f : (c - (float)lo);
    }
    __syncthreads();

    // per-thread copies: col fracs + LDS offsets for this thread's channel
    float cf[14]; int cof[14];
    #pragma unroll
    for (int j = 0; j < 14; ++j) {
        cf[j]  = s_cf[j];
        cof[j] = tid * HPAD + s_cl[j];
    }

    // ---- staging setup: lanes = (channel-group 0..7) x (col 0..31) ----
    const int span = h + 1;                // cols staged per row: y .. y+h
    const int col  = tid & 31;
    const int cg   = tid >> 5;             // channel = cg + 8*k, k=0..31
    const float* fb = features + ((size_t)b * 256 + cg) * 2500
                               + (size_t)x * 50 + y + col;

    auto stage = [&](int p, int s) {
        if (col < span) {
            const float* g = fb + p * 50;
            float* d = slots + s * SLOT + cg * HPAD + col;
            #pragma unroll
            for (int k = 0; k < 32; ++k) {
                d[k * 8 * HPAD] = g[k * 8 * 2500];
            }
        }
    };

    // col-lerp one staged physical row into M[14] for this thread's channel
    auto collerp = [&](int s, float* M) {
        const float* sb = slots + s * SLOT;
        #pragma unroll
        for (int j = 0; j < 14; ++j) {
            const float lo = sb[cof[j]];
            const float hi = sb[cof[j] + 1];   // cl+1 <= h: always staged
            M[j] = lo + cf[j] * (hi - lo);     // frac==0 when clamped
        }
    };

    // ---- main: stream physical rows 0..w, accumulate res[49] in regs ----
    float M0[14], M1[14], res[49];
    stage(0, 0);
    __syncthreads();
    collerp(0, M1);                         // M1 = physical row 0

    int i = 0;                              // interp-row pointer (uniform)
    for (int p = 1; p <= w; ++p) {
        #pragma unroll
        for (int j = 0; j < 14; ++j) M0[j] = M1[j];
        __syncthreads();                    // everyone done reading slot p&1
        stage(p, p & 1);
        __syncthreads();
        collerp(p & 1, M1);                 // M1 = physical row p
        // emit all interp rows whose low row == p-1 (rl non-decreasing)
        while (i < 14 && s_rl[i] == p - 1) {
            const float rf = s_rf[i];
            #pragma unroll
            for (int q = 0; q < 7; ++q) {
                const float a = M0[2 * q]     + rf * (M1[2 * q]     - M0[2 * q]);
                const float c = M0[2 * q + 1] + rf * (M1[2 * q + 1] - M0[2 * q + 1]);
                const float m = fmaxf(a, c);
                const int o = (i >> 1) * 7 + q;
                if (i & 1) res[o] = fmaxf(res[o], m);
                else       res[o] = m;
            }
            ++i;
        }
    }

    // ---- coalesced epilogue: regs -> LDS -> float4 full-line stores ----
    __syncthreads();                        // all collerp reads of slots done
    {
        float* sbuf = slots;                // reuse: need 12544 <= 12800 floats
        #pragma unroll
        for (int j = 0; j < 49; ++j)        // stride-49: 2-way bank alias, free
            sbuf[tid * 49 + j] = res[j];
    }
    __syncthreads();
    {
        const float4* sv = (const float4*)slots;        // 3136 float4s
        float4* ov = (float4*)(out + (size_t)bid * 12544); // 16B-aligned
        #pragma unroll
        for (int k = 0; k < 13; ++k) {
            const int idx = k * 256 + tid;
            if (idx < 3136) ov[idx] = sv[idx];
        }
    }
}

extern "C" void kernel_launch(void* const* d_in, const int* in_sizes, int n_in,
                              void* d_out, int out_size, void* d_ws, size_t ws_size,
                              hipStream_t stream) {
    const float* proposals = (const float*)d_in[0];   // (4,512,4)
    const float* features  = (const float*)d_in[1];   // (4,256,50,50)
    float* outp = (float*)d_out;                      // 25,690,112 floats
    roi_kernel<<<dim3(2048), dim3(256), 0, stream>>>(proposals, features, outp);
}

// Round 3
// 210.302 us; speedup vs baseline: 1.3472x; 1.2321x over previous
//
#include <hip/hip_runtime.h>

// ROI align (14x14 bilinear grid) + 2x2 maxpool -> 7x7 per (b,n,c).
// B=4, N=512, C=256, feature plane 50x50 f32, out (4,512,256,7,7) f32.
//
// R2 lesson: res[]/pool[] with runtime indices spilled to scratch (VGPR=68
// proved it) -> ~300 MB of hidden scratch HBM traffic. All register arrays
// below are indexed with compile-time constants only.
//
// Structure: block = 256 threads = 4 AUTONOMOUS waves; wave owns 64 channels
// of one proposal and a private 64x25-float LDS row buffer. Main loop has NO
// __syncthreads (no vmcnt(0) barrier drains): per physical row, the wave
//   - ds_write2s the prefetched row (regs R) into its buffer,
//   - issues float2 global loads for the next row into R,
//   - waits lgkmcnt(0) (intra-wave), col-lerps its channel's row from LDS,
//   - row-lerps + pools into res[49] (static indices).
// Epilogue: per-wave, 2 chunks of 32 channels staged through the same buffer,
// written with lane-consecutive float4 stores (full-line writes).

#define HPAD 25              // LDS row stride (odd -> 2-way bank alias = free)
#define WBUF 1600            // per-wave floats (64*25); >= 32*49=1568 epilogue

__global__ __launch_bounds__(256, 3) void roi_kernel(
    const float* __restrict__ proposals,   // (4,512,4)  [x,y,w,h]
    const float* __restrict__ features,    // (4,256,50,50)
    float* __restrict__ out)               // (4,512,256,7,7)
{
    const int bid  = blockIdx.x;           // b*512+n
    const int b    = bid >> 9;
    const int tid  = threadIdx.x;
    const int wv   = tid >> 6;             // wave 0..3 -> channels wv*64+lane
    const int lane = tid & 63;

    __shared__ float s_cf[16];
    __shared__ int   s_cl[16];
    __shared__ float s_rf[16];             // kept for layout symmetry
    __shared__ int   s_rl[16];
    __shared__ float buf[4][WBUF];         // 25.6 KB total

    // ---- proposal -> integer box (numpy f32 semantics) ----
    const float4 prop = *(const float4*)(proposals + (size_t)bid * 4);
    const int x = (int)(prop.x * 0.0625f);   // row start   (50/800)
    const int y = (int)(prop.y * 0.0625f);   // col start
    const int w = (int)(prop.z * 0.0625f);   // row extent  (5..22)
    const int h = (int)(prop.w * 0.0625f);   // col extent  (5..22)

    if (tid < 14) {
        const float sc = (float)(w - 1) / 13.0f;
        const float c  = (float)tid * sc;
        const int lo   = (int)c;
        s_rl[tid] = lo;
        s_rf[tid] = (lo + 1 > w - 1) ? 0.0f : (c - (float)lo);
    } else if (tid >= 64 && tid < 78) {
        const int j    = tid - 64;
        const float sc = (float)(h - 1) / 13.0f;
        const float c  = (float)j * sc;
        const int lo   = (int)c;
        s_cl[j] = lo;
        s_cf[j] = (lo + 1 > h - 1) ? 0.0f : (c - (float)lo);
    }
    __syncthreads();                       // ONLY block barrier in the kernel

    // ---- per-thread uniform tables (compile-time indexed) ----
    const int shift = y & 1;               // align float2 loads to 8 B
    const int y2    = y - shift;
    const int hh    = h + shift;           // needed cols rel y2: 0..hh (<=23)

    float cf[14]; int cof[14]; int rls[14];
    #pragma unroll
    for (int j = 0; j < 14; ++j) {
        cf[j]  = s_cf[j];
        cof[j] = lane * HPAD + shift + s_cl[j];
        rls[j] = __builtin_amdgcn_readfirstlane(s_rl[j]);   // wave-uniform
    }

    // ---- staging lanes: (cg 0..3) x (col2 0..15); chunk k -> ch 4k+cg ----
    const int  cg   = lane >> 4;
    const int  col2 = lane & 15;
    const bool act  = (2 * col2) <= hh;    // hh<=23 -> col2<=11 active
    const float* gbase = features
        + ((size_t)(b * 256 + wv * 64 + cg)) * 2500
        + (size_t)x * 50 + y2 + 2 * col2;
    float* const wbuf = buf[wv];

    float2 R[16];                          // prefetched row (one ahead)
    float  M0[14], M1[14], res[49];

    auto ldrow = [&](int p) {
        if (act) {
            const float* g = gbase + p * 50;
            #pragma unroll
            for (int k = 0; k < 16; ++k)
                R[k] = *(const float2*)(g + k * 10000);   // 4 ch * 2500
        }
    };
    auto wrrow = [&]() {
        if (act) {
            #pragma unroll
            for (int k = 0; k < 16; ++k) {
                const int a = (4 * k + cg) * HPAD + 2 * col2;
                wbuf[a]     = R[k].x;      // merges to ds_write2_b32
                wbuf[a + 1] = R[k].y;
            }
        }
    };
    auto collerp = [&](float* M) {
        #pragma unroll
        for (int j = 0; j < 14; ++j) {
            const float lo = wbuf[cof[j]];
            const float hi = wbuf[cof[j] + 1];   // ds_read2_b32 pair
            M[j] = lo + cf[j] * (hi - lo);       // frac==0 when clamped
        }
    };

    // ---- main loop: stream physical rows 0..w, no block barriers ----
    ldrow(0);
    wrrow();                               // row 0 -> LDS (vmcnt auto-waited)
    ldrow(1);                              // prefetch row 1
    asm volatile("s_waitcnt lgkmcnt(0)" ::: "memory");
    collerp(M1);                           // M1 = row 0

    const float rsc = (float)(w - 1) / 13.0f;

    for (int p = 1; p <= w; ++p) {
        #pragma unroll
        for (int j = 0; j < 14; ++j) M0[j] = M1[j];   // consumes M1 reads
        wrrow();                           // row p -> LDS (R holds row p)
        if (p < w) ldrow(p + 1);           // prefetch next
        asm volatile("s_waitcnt lgkmcnt(0)" ::: "memory");
        collerp(M1);                       // M1 = row p
        // emit interp rows i with rl[i] == p-1 (static unroll, uniform guard)
        #pragma unroll
        for (int i2 = 0; i2 < 14; ++i2) {
            if (rls[i2] == p - 1) {
                float rf = (float)i2 * rsc - (float)rls[i2];
                if (rls[i2] + 1 > w - 1) rf = 0.0f;
                #pragma unroll
                for (int q = 0; q < 7; ++q) {
                    const float a0 = M0[2*q]   + rf * (M1[2*q]   - M0[2*q]);
                    const float a1 = M0[2*q+1] + rf * (M1[2*q+1] - M0[2*q+1]);
                    const float m  = fmaxf(a0, a1);
                    const int  o   = (i2 >> 1) * 7 + q;       // compile-time
                    if (i2 & 1) res[o] = fmaxf(res[o], m);
                    else        res[o] = m;
                }
            }
        }
    }

    // ---- per-wave epilogue: 2 chunks of 32 channels via LDS, float4 out ----
    #pragma unroll
    for (int half = 0; half < 2; ++half) {
        asm volatile("s_waitcnt lgkmcnt(0)" ::: "memory");
        if ((lane >> 5) == half) {
            const int l32 = lane & 31;
            #pragma unroll
            for (int j = 0; j < 49; ++j)   // stride 49: 32 banks, no conflict
                wbuf[l32 * 49 + j] = res[j];
        }
        asm volatile("s_waitcnt lgkmcnt(0)" ::: "memory");
        const float4* sv = (const float4*)wbuf;          // 392 float4s
        float4* ov = (float4*)(out + (size_t)bid * 12544)
                   + (wv * 2 + half) * 392;
        #pragma unroll
        for (int k = 0; k < 7; ++k) {
            const int idx = k * 64 + lane;
            if (idx < 392) ov[idx] = sv[idx];
        }
    }
}

extern "C" void kernel_launch(void* const* d_in, const int* in_sizes, int n_in,
                              void* d_out, int out_size, void* d_ws, size_t ws_size,
                              hipStream_t stream) {
    const float* proposals = (const float*)d_in[0];   // (4,512,4)
    const float* features  = (const float*)d_in[1];   // (4,256,50,50)
    float* outp = (float*)d_out;                      // 25,690,112 floats
    roi_kernel<<<dim3(2048), dim3(256), 0, stream>>>(proposals, features, outp);
}